// Round 8
// baseline (6687.495 us; speedup 1.0000x reference)
//
#include <hip/hip_runtime.h>

typedef short short8 __attribute__((ext_vector_type(8)));
typedef float f32x4 __attribute__((ext_vector_type(4)));
typedef unsigned u32x4 __attribute__((ext_vector_type(4)));

#define DD 4096
#define KSL 4         // split-K factor
#define KSLAB 1024    // k-rows per block
#define NIT 32        // k-tiles of 32 rows
#define NLAYER 15

__device__ __forceinline__ unsigned short f2bf(float f) {
  unsigned u = __float_as_uint(f);
  u += 0x7FFFu + ((u >> 16) & 1u);   // RTNE (cold paths)
  return (unsigned short)(u >> 16);
}
__device__ __forceinline__ float bf2f(unsigned short b) {
  return __uint_as_float(((unsigned)b) << 16);
}
// hot path: two f32 -> packed bf16 pair, round-half-away-from-zero (unbiased)
__device__ __forceinline__ unsigned pack2(float a, float b) {
  unsigned ua = __float_as_uint(a) + 0x8000u;
  unsigned ub = __float_as_uint(b) + 0x8000u;
  return (ua >> 16) | (ub & 0xFFFF0000u);
}

// fp32 x [256][4096] -> bf16 h blocked [k>>5][m 256][k&31]
__global__ __launch_bounds__(256) void k_tobf16(const float* __restrict__ x,
                                                unsigned short* __restrict__ h) {
  const size_t e = ((size_t)blockIdx.x * 256 + threadIdx.x) * 8;
  const int m = (int)(e >> 12), n = (int)(e & (DD - 1));
  f32x4 a = *(const f32x4*)(x + e);
  f32x4 b = *(const f32x4*)(x + e + 4);
  short8 v;
#pragma unroll
  for (int j = 0; j < 4; ++j) { v[j] = (short)f2bf(a[j]); v[4 + j] = (short)f2bf(b[j]); }
  *(short8*)(h + (size_t)(n >> 5) * 8192 + m * 32 + (n & 31)) = v;
}

// 4x4 quad transpose across p-lane groups (verified R3-R6), pack2 convert
__device__ __forceinline__ void qtrans(f32x4 v, int p, unsigned& lo, unsigned& hi) {
  unsigned d0 = pack2(v[0], v[1]);
  unsigned d1 = pack2(v[2], v[3]);
  unsigned o0 = (unsigned)__shfl_xor((int)d0, 16);
  unsigned o1 = (unsigned)__shfl_xor((int)d1, 16);
  unsigned r0, r1;
  if ((p & 1) == 0) { r0 = (d0 & 0xFFFFu) | (o0 << 16); r1 = (d0 >> 16) | (o0 & 0xFFFF0000u); }
  else              { r0 = (o1 & 0xFFFFu) | (d1 << 16); r1 = (o1 >> 16) | (d1 & 0xFFFF0000u); }
  unsigned q0 = (unsigned)__shfl_xor((int)r0, 32);
  unsigned q1 = (unsigned)__shfl_xor((int)r1, 32);
  if (p < 2) { lo = r0; hi = q0; } else { lo = q1; hi = r1; }
}

// Split-K GEMM partial: block (mb, nb, ks) = [16 m x 1024 n] over k in [ks*1024,+1024).
// Per k-row the block reads 4KB contiguous W. Each wave owns a private 64-n strip:
// stages (qtrans->bf16) into its own 4KB LDS region and consumes it itself ->
// NO __syncthreads anywhere. W register pipeline depth 2; A blocked bf16 via L1.
__global__ __launch_bounds__(1024) void k_gemm(const unsigned short* __restrict__ A,
                                               const float* __restrict__ W,
                                               unsigned short* __restrict__ part) {
  __shared__ __align__(16) unsigned char smem[65536];   // 16 waves x 4KB private
  const int bid  = blockIdx.x;
  const int ks   = bid & 3;
  const int nb   = (bid >> 2) & 3;
  const int mb   = bid >> 4;
  const int tid  = threadIdx.x;
  const int lane = tid & 63;
  const int wave = tid >> 6;        // 0..15
  const int l15  = lane & 15;
  const int p    = lane >> 4;       // 0..3
  const int pp   = ((p & 1) << 1) | (p >> 1);
  const int nw   = 4 * l15 + pp;    // transposed n-col within the wave's 64-strip

  // W source: k-row = ks*1024 + it*32 + 8*kg + p (+4); n = nb*1024 + wave*64 + 4*l15
  const float* wsrc = W + (size_t)(ks * KSLAB + p) * DD + nb * 1024 + wave * 64 + 4 * l15;
  // A blocked [kb][m 256][32]; kb = ks*32 + it
  const unsigned short* Ab = A + (size_t)(ks * 32) * 8192 + (mb * 16 + l15) * 32 + p * 8;
  unsigned char* myl = smem + wave * 4096;   // private: [kg 4][nw 64][16B]

  const f32x4 fz = {0.f, 0.f, 0.f, 0.f};
  f32x4 acc[4] = {fz, fz, fz, fz};
  f32x4 wr[2][8];        // depth-2 W pipeline: 8 f32x4 = one 32k x 64n wave-tile
  short8 ar[2];

#define LOADW(T, S)                                                        \
  do {                                                                     \
    _Pragma("unroll")                                                      \
    for (int kg = 0; kg < 4; ++kg) {                                       \
      wr[S][2*kg]   = *(const f32x4*)(wsrc + (size_t)((T)*32 + 8*kg) * DD);   \
      wr[S][2*kg+1] = *(const f32x4*)(wsrc + (size_t)((T)*32 + 8*kg+4) * DD); \
    }                                                                      \
  } while (0)

#define STAGE(S)                                                           \
  do {                                                                     \
    _Pragma("unroll")                                                      \
    for (int kg = 0; kg < 4; ++kg) {                                       \
      unsigned la, ha, lb, hb;                                             \
      qtrans(wr[S][2*kg],   p, la, ha);                                    \
      qtrans(wr[S][2*kg+1], p, lb, hb);                                    \
      u32x4 v = {la, ha, lb, hb};                                          \
      *(u32x4*)(myl + kg * 1024 + nw * 16) = v;                            \
    }                                                                      \
  } while (0)

  // prologue: tiles 0,1 in regs; stage tile 0; A-frag 0
  LOADW(0, 0);
  LOADW(1, 1);
  ar[0] = *(const short8*)(Ab);
  STAGE(0);

  for (int it = 0; it < NIT; ++it) {
    if (it + 2 < NIT) LOADW(it + 2, it & 1);
    if (it + 1 < NIT) ar[(it + 1) & 1] = *(const short8*)(Ab + (size_t)(it + 1) * 8192);
    // consume tile it from private LDS (staged last iter); reads precede overwrite
#pragma unroll
    for (int nf = 0; nf < 4; ++nf) {
      short8 bf = *(const short8*)(myl + p * 1024 + (16 * nf + l15) * 16);
      acc[nf] = __builtin_amdgcn_mfma_f32_16x16x32_bf16(ar[it & 1], bf, acc[nf], 0, 0, 0);
    }
    if (it + 1 < NIT) STAGE((it + 1) & 1);
  }
#undef LOADW
#undef STAGE

  // bf16 partial write [ks][m 256][n 4096]; pair adjacent cols via lane shuffle
  unsigned short* pl = part + (size_t)ks * (256 * 4096);
  const int nbase = nb * 1024 + wave * 64;
#pragma unroll
  for (int nf = 0; nf < 4; ++nf) {
    f32x4 a = acc[nf], o;
#pragma unroll
    for (int j = 0; j < 4; ++j) o[j] = __shfl_xor(a[j], 1);
    if ((l15 & 1) == 0) {
      const int n = nbase + 16 * nf + l15;
      const int m = mb * 16 + 4 * p;
#pragma unroll
      for (int j = 0; j < 4; ++j) {
        unsigned pk = (unsigned)f2bf(a[j]) | ((unsigned)f2bf(o[j]) << 16);
        *(unsigned*)((char*)pl + ((size_t)(m + j) * 4096 + n) * 2) = pk;
      }
    }
  }
}

// sum 4 bf16 partials + bias, relu -> bf16 blocked h (+ fp32 out on last layer)
__global__ __launch_bounds__(256) void k_reduce(const unsigned short* __restrict__ part,
                                                const float* __restrict__ bias,
                                                unsigned short* __restrict__ hout,
                                                float* __restrict__ fout) {
  const size_t e = ((size_t)blockIdx.x * 256 + threadIdx.x) * 8;
  float s[8] = {0.f, 0.f, 0.f, 0.f, 0.f, 0.f, 0.f, 0.f};
#pragma unroll
  for (int ks = 0; ks < KSL; ++ks) {
    short8 v = *(const short8*)(part + (size_t)ks * (256 * 4096) + e);
#pragma unroll
    for (int j = 0; j < 8; ++j) s[j] += bf2f((unsigned short)v[j]);
  }
  const int m = (int)(e >> 12), n = (int)(e & (DD - 1));
#pragma unroll
  for (int j = 0; j < 8; ++j) s[j] = fmaxf(s[j] + bias[n + j], 0.f);
  short8 o;
#pragma unroll
  for (int j = 0; j < 8; ++j) o[j] = (short)f2bf(s[j]);
  *(short8*)(hout + (size_t)(n >> 5) * 8192 + m * 32 + (n & 31)) = o;
  if (fout) {
    f32x4 o0, o1;
#pragma unroll
    for (int j = 0; j < 4; ++j) { o0[j] = s[j]; o1[j] = s[4 + j]; }
    float* dst = fout + e;
    *(f32x4*)dst = o0;
    *(f32x4*)(dst + 4) = o1;
  }
}

extern "C" void kernel_launch(void* const* d_in, const int* in_sizes, int n_in,
                              void* d_out, int out_size, void* d_ws, size_t ws_size,
                              hipStream_t stream) {
  const float* x = (const float*)d_in[0];
  const float* W = (const float*)d_in[1];
  const float* b = (const float*)d_in[2];
  float* out = (float*)d_out;

  char* ws = (char*)d_ws;
  unsigned short* h0 = (unsigned short*)ws;                 // 2 MB bf16 blocked
  unsigned short* h1 = (unsigned short*)(ws + (1 << 21));   // 2 MB
  unsigned short* part = (unsigned short*)(ws + (1 << 22)); // 4 x 2 MB bf16 partials

  k_tobf16<<<512, 256, 0, stream>>>(x, h0);
  unsigned short* hc = h0;
  unsigned short* hn = h1;
  for (int l = 0; l < NLAYER; ++l) {
    const bool last = (l == NLAYER - 1);
    k_gemm<<<256, 1024, 0, stream>>>(hc, W + (size_t)l * DD * DD, part);
    k_reduce<<<512, 256, 0, stream>>>(part, b + (size_t)l * DD, hn,
                                      last ? out : nullptr);
    unsigned short* t = hc; hc = hn; hn = t;
  }
}

// Round 9
// 998.103 us; speedup vs baseline: 6.7002x; 6.7002x over previous
//
#include <hip/hip_runtime.h>

typedef short short8 __attribute__((ext_vector_type(8)));
typedef float f32x4 __attribute__((ext_vector_type(4)));
typedef unsigned u32x4 __attribute__((ext_vector_type(4)));

#define DD 4096
#define KSL 4         // split-K; partials 4 x 2MB bf16
#define KSLAB 1024    // k-rows per block
#define NIT 32        // k-tiles of 32 rows
#define NLAYER 15

__device__ __forceinline__ unsigned short f2bf(float f) {
  unsigned u = __float_as_uint(f);
  u += 0x7FFFu + ((u >> 16) & 1u);   // RTNE (cold paths)
  return (unsigned short)(u >> 16);
}
__device__ __forceinline__ float bf2f(unsigned short b) {
  return __uint_as_float(((unsigned)b) << 16);
}
// hot path: two f32 -> packed bf16 pair, round-half-away (verified R8: absmax equal)
__device__ __forceinline__ unsigned pack2(float a, float b) {
  unsigned ua = __float_as_uint(a) + 0x8000u;
  unsigned ub = __float_as_uint(b) + 0x8000u;
  return (ua >> 16) | (ub & 0xFFFF0000u);
}

// fp32 x [256][4096] -> bf16 h blocked [k>>5][m 256][k&31]
__global__ __launch_bounds__(256) void k_tobf16(const float* __restrict__ x,
                                                unsigned short* __restrict__ h) {
  const size_t e = ((size_t)blockIdx.x * 256 + threadIdx.x) * 8;
  const int m = (int)(e >> 12), n = (int)(e & (DD - 1));
  f32x4 a = *(const f32x4*)(x + e);
  f32x4 b = *(const f32x4*)(x + e + 4);
  short8 v;
#pragma unroll
  for (int j = 0; j < 4; ++j) { v[j] = (short)f2bf(a[j]); v[4 + j] = (short)f2bf(b[j]); }
  *(short8*)(h + (size_t)(n >> 5) * 8192 + m * 32 + (n & 31)) = v;
}

// 4x4 quad transpose across p-lane groups (verified R3-R8)
__device__ __forceinline__ void qtrans(f32x4 v, int p, unsigned& lo, unsigned& hi) {
  unsigned d0 = pack2(v[0], v[1]);
  unsigned d1 = pack2(v[2], v[3]);
  unsigned o0 = (unsigned)__shfl_xor((int)d0, 16);
  unsigned o1 = (unsigned)__shfl_xor((int)d1, 16);
  unsigned r0, r1;
  if ((p & 1) == 0) { r0 = (d0 & 0xFFFFu) | (o0 << 16); r1 = (d0 >> 16) | (o0 & 0xFFFF0000u); }
  else              { r0 = (o1 & 0xFFFFu) | (d1 << 16); r1 = (o1 >> 16) | (d1 & 0xFFFF0000u); }
  unsigned q0 = (unsigned)__shfl_xor((int)r0, 32);
  unsigned q1 = (unsigned)__shfl_xor((int)r1, 32);
  if (p < 2) { lo = r0; hi = q0; } else { lo = q1; hi = r1; }
}

// Split-K GEMM partial: block (mb,nb,ks) = [32 m x 512 n] over k [ks*1024,+1024).
// Per k-row the block reads 2KB contiguous W (8 waves x 256B, issued in lockstep).
// Each wave stages ITS OWN 64-n strip (qtrans -> frag-blocked LDS, wave-private),
// double-buffered; depth-2 W register pipeline; FULLY UNROLLED (static indexing).
__global__ __launch_bounds__(512, 2) void k_gemm(const unsigned short* __restrict__ A,
                                                 const float* __restrict__ W,
                                                 unsigned short* __restrict__ part) {
  __shared__ __align__(16) unsigned char smem[65536];  // 2 buf x [4 kg][512 n][16B]
  const int bid  = blockIdx.x;
  const int mb   = bid >> 5;          // 0..7 (stride 32 -> slab-sharing blocks co-XCD)
  const int nb   = (bid >> 2) & 7;    // 0..7
  const int ks   = bid & 3;
  const int tid  = threadIdx.x;
  const int lane = tid & 63;
  const int wave = tid >> 6;          // 0..7
  const int l15  = lane & 15;
  const int p    = lane >> 4;         // 0..3
  const int pp   = ((p & 1) << 1) | (p >> 1);
  const int nw   = 4 * l15 + pp;      // transposed n-col within wave's 64-strip

  // W: k-row ks*1024 + it*32 + 4*ss + p ; n = nb*512 + wave*64 + 4*l15
  const float* wsrc = W + (size_t)(ks * KSLAB + p) * DD + nb * 512 + wave * 64 + 4 * l15;
  // A blocked [kb][256 m][32]; kb = ks*32 + it; rows mb*32 + mf*16 + l15
  const unsigned short* Ab = A + (size_t)(ks * 32) * 8192 + (mb * 32 + l15) * 32 + p * 8;
  unsigned char* stb = smem + (wave * 64 + nw) * 16;                  // + buf*32768 + g*8192
  const unsigned char* cb = smem + p * 8192 + (wave * 64 + l15) * 16; // + buf*32768 + nf*256

  const f32x4 fz = {0.f, 0.f, 0.f, 0.f};
  f32x4 acc[2][4];
#pragma unroll
  for (int i = 0; i < 2; ++i)
#pragma unroll
    for (int j = 0; j < 4; ++j) acc[i][j] = fz;

  f32x4 wr[2][8];      // depth-2 W pipeline (one 32k x 64n wave-slice per slot)
  short8 ar[2][2];     // A frags, [slot][mf]

#define LOADW(T, S)                                                        \
  do {                                                                     \
    _Pragma("unroll")                                                      \
    for (int ss = 0; ss < 8; ++ss)                                         \
      wr[S][ss] = *(const f32x4*)(wsrc + (size_t)((T) * 32 + 4 * ss) * DD); \
  } while (0)

#define LOADA(T, S)                                                        \
  do {                                                                     \
    ar[S][0] = *(const short8*)(Ab + (size_t)(T) * 8192);                  \
    ar[S][1] = *(const short8*)(Ab + (size_t)(T) * 8192 + 512);            \
  } while (0)

#define STAGE(S, BUF)                                                      \
  do {                                                                     \
    _Pragma("unroll")                                                      \
    for (int g = 0; g < 4; ++g) {                                          \
      unsigned la, ha, lb, hb;                                             \
      qtrans(wr[S][2 * g], p, la, ha);                                     \
      qtrans(wr[S][2 * g + 1], p, lb, hb);                                 \
      u32x4 v = {la, ha, lb, hb};                                          \
      *(u32x4*)(stb + (BUF) * 32768 + g * 8192) = v;                       \
    }                                                                      \
  } while (0)

  // prologue: W tiles 0,1 in regs; A frag 0; stage tile 0 -> buf 0
  LOADW(0, 0);
  LOADW(1, 1);
  LOADA(0, 0);
  STAGE(0, 0);
  __syncthreads();

#pragma unroll
  for (int it = 0; it < NIT; ++it) {
    if (it + 2 < NIT) LOADW(it + 2, it & 1);     // slot (it&1) was staged last iter
    if (it + 1 < NIT) LOADA(it + 1, (it + 1) & 1);
    const unsigned char* cbb = cb + (it & 1) * 32768;
#pragma unroll
    for (int nf = 0; nf < 4; ++nf) {
      short8 bf = *(const short8*)(cbb + nf * 256);
#pragma unroll
      for (int mf = 0; mf < 2; ++mf)
        acc[mf][nf] = __builtin_amdgcn_mfma_f32_16x16x32_bf16(ar[it & 1][mf], bf,
                                                              acc[mf][nf], 0, 0, 0);
    }
    if (it + 1 < NIT) STAGE((it + 1) & 1, (it + 1) & 1);  // waits vmcnt on its slot
    __syncthreads();   // lockstep: all waves issue next LOADW together
  }
#undef LOADW
#undef LOADA
#undef STAGE

  // bf16 partial write [ks][256 m][4096 n]; pair adjacent cols via lane shuffle
  unsigned short* pl = part + (size_t)ks * (256 * 4096)
                     + (size_t)(mb * 32) * 4096 + nb * 512 + wave * 64;
#pragma unroll
  for (int mf = 0; mf < 2; ++mf)
#pragma unroll
    for (int nf = 0; nf < 4; ++nf) {
      f32x4 a = acc[mf][nf], o;
#pragma unroll
      for (int j = 0; j < 4; ++j) o[j] = __shfl_xor(a[j], 1);
      if ((l15 & 1) == 0) {
#pragma unroll
        for (int j = 0; j < 4; ++j) {
          unsigned pk = (unsigned)f2bf(a[j]) | ((unsigned)f2bf(o[j]) << 16);
          *(unsigned*)((char*)pl +
              (((size_t)(mf * 16 + 4 * p + j)) * 4096 + nf * 16 + l15) * 2) = pk;
        }
      }
    }
}

// sum 4 bf16 partials + bias, relu -> bf16 blocked h (+ fp32 out on last layer)
__global__ __launch_bounds__(256) void k_reduce(const unsigned short* __restrict__ part,
                                                const float* __restrict__ bias,
                                                unsigned short* __restrict__ hout,
                                                float* __restrict__ fout) {
  const size_t e = ((size_t)blockIdx.x * 256 + threadIdx.x) * 8;
  float s[8] = {0.f, 0.f, 0.f, 0.f, 0.f, 0.f, 0.f, 0.f};
#pragma unroll
  for (int ks = 0; ks < KSL; ++ks) {
    short8 v = *(const short8*)(part + (size_t)ks * (256 * 4096) + e);
#pragma unroll
    for (int j = 0; j < 8; ++j) s[j] += bf2f((unsigned short)v[j]);
  }
  const int m = (int)(e >> 12), n = (int)(e & (DD - 1));
#pragma unroll
  for (int j = 0; j < 8; ++j) s[j] = fmaxf(s[j] + bias[n + j], 0.f);
  short8 o;
#pragma unroll
  for (int j = 0; j < 8; ++j) o[j] = (short)f2bf(s[j]);
  *(short8*)(hout + (size_t)(n >> 5) * 8192 + m * 32 + (n & 31)) = o;
  if (fout) {
    f32x4 o0, o1;
#pragma unroll
    for (int j = 0; j < 4; ++j) { o0[j] = s[j]; o1[j] = s[4 + j]; }
    float* dst = fout + e;
    *(f32x4*)dst = o0;
    *(f32x4*)(dst + 4) = o1;
  }
}

extern "C" void kernel_launch(void* const* d_in, const int* in_sizes, int n_in,
                              void* d_out, int out_size, void* d_ws, size_t ws_size,
                              hipStream_t stream) {
  const float* x = (const float*)d_in[0];
  const float* W = (const float*)d_in[1];
  const float* b = (const float*)d_in[2];
  float* out = (float*)d_out;

  char* ws = (char*)d_ws;
  unsigned short* h0 = (unsigned short*)ws;                 // 2 MB bf16 blocked
  unsigned short* h1 = (unsigned short*)(ws + (1 << 21));   // 2 MB
  unsigned short* part = (unsigned short*)(ws + (1 << 22)); // 4 x 2 MB bf16 partials

  k_tobf16<<<512, 256, 0, stream>>>(x, h0);
  unsigned short* hc = h0;
  unsigned short* hn = h1;
  for (int l = 0; l < NLAYER; ++l) {
    const bool last = (l == NLAYER - 1);
    k_gemm<<<256, 512, 0, stream>>>(hc, W + (size_t)l * DD * DD, part);
    k_reduce<<<512, 256, 0, stream>>>(part, b + (size_t)l * DD, hn,
                                      last ? out : nullptr);
    unsigned short* t = hc; hc = hn; hn = t;
  }
}